// Round 2
// baseline (23672.060 us; speedup 1.0000x reference)
//
#include <hip/hip_runtime.h>
#include <stdint.h>

// Problem constants (from reference: points_xyz (16, 131072, 3) fp32, NUM_POINT=4096)
#define BATCH 16
#define NPTS  131072
#define NSAMP 4096
#define NBLK  16                  // blocks per batch (16*16 = 256 blocks = 1/CU)
#define TPB   1024
#define CHUNK (NPTS / NBLK)       // 8192 points per block
#define PPT   (CHUNK / TPB)       // 8 points per thread, register-resident
#define NWAVE (TPB / 64)          // 16 waves per block

// Workspace layout:
//   unsigned long long slot[BATCH][NSAMP]   (packed argmax combine, 512 KB)
//   unsigned int       cnt [BATCH][NSAMP]   (arrival counters,       256 KB)
// One slot/counter per iteration -> no reset races; zeroed each launch.

__global__ void fps_init_kernel(unsigned int* __restrict__ ws, int n) {
    int i = blockIdx.x * blockDim.x + threadIdx.x;
    if (i < n) ws[i] = 0u;
}

__global__ __launch_bounds__(TPB, 4) void fps_kernel(
        const float* __restrict__ xyz, int* __restrict__ out,
        unsigned long long* __restrict__ slot, unsigned int* __restrict__ cnt) {
    const int blk   = blockIdx.x;
    const int b     = blk >> 4;        // batch  = blk / NBLK
    const int chunk = blk & (NBLK - 1);
    const int tid   = threadIdx.x;

    const float* bxyz = xyz + (size_t)b * NPTS * 3;
    const int base = chunk * CHUNK;    // first point index of this block's chunk

    // Register-resident points + running min distance
    float px[PPT], py[PPT], pz[PPT], pd[PPT];
#pragma unroll
    for (int k = 0; k < PPT; ++k) {
        int p = base + tid + k * TPB;
        px[k] = bxyz[3 * (size_t)p + 0];
        py[k] = bxyz[3 * (size_t)p + 1];
        pz[k] = bxyz[3 * (size_t)p + 2];
        pd[k] = __builtin_inff();
    }

    __shared__ unsigned long long red[NWAVE];
    __shared__ float scx, scy, scz;

    // Iteration 0: emitted index is 0, centroid = point 0 of the batch.
    if (tid == 0) {
        scx = bxyz[0]; scy = bxyz[1]; scz = bxyz[2];
        if (chunk == 0) out[b * NSAMP] = 0;
    }
    __syncthreads();
    float cx = scx, cy = scy, cz = scz;

    unsigned long long* bslot = slot + (size_t)b * NSAMP;
    unsigned int*       bcnt  = cnt  + (size_t)b * NSAMP;

    for (int it = 1; it < NSAMP; ++it) {
        // ---- update min-dists + local argmax (pure VALU, registers only) ----
        // Arithmetic model: XLA reduce with FMA contraction —
        //   acc = dx*dx; acc = fma(dy,dy,acc); acc = fma(dz,dz,acc)
        // (strict unfused ((dx2+dy2)+dz2) produced a single near-tie argmax
        //  flip vs the reference trajectory in round 1 — absmax 38144 ≈ one
        //  swapped pick. FMA-contracted sum is the canonical XLA emission.)
        unsigned long long best = 0ull;
#pragma unroll
        for (int k = 0; k < PPT; ++k) {
            float dx = __fsub_rn(px[k], cx);
            float dy = __fsub_rn(py[k], cy);
            float dz = __fsub_rn(pz[k], cz);
            float d  = __builtin_fmaf(dz, dz,
                         __builtin_fmaf(dy, dy, __fmul_rn(dx, dx)));
            float nd = fminf(pd[k], d);
            pd[k] = nd;
            // Pack: high 32 = dist bits (monotone for non-negative floats),
            // low 32 = ~idx so max-packed resolves equal dists to SMALLEST idx
            // (jnp.argmax picks first occurrence).
            unsigned int gi = (unsigned int)(base + tid + k * TPB);
            unsigned long long pk =
                ((unsigned long long)__float_as_uint(nd) << 32) |
                (unsigned long long)(~gi);
            best = best > pk ? best : pk;
        }

        // ---- wave reduction (64 lanes) ----
#pragma unroll
        for (int off = 32; off >= 1; off >>= 1) {
            unsigned long long o = __shfl_down(best, off, 64);
            best = best > o ? best : o;
        }
        if ((tid & 63) == 0) red[tid >> 6] = best;
        __syncthreads();

        // ---- thread 0: block combine, cross-block combine, spin barrier ----
        if (tid == 0) {
            unsigned long long m = red[0];
#pragma unroll
            for (int w = 1; w < NWAVE; ++w) m = m > red[w] ? m : red[w];

            __hip_atomic_fetch_max(&bslot[it], m, __ATOMIC_RELAXED,
                                   __HIP_MEMORY_SCOPE_AGENT);
            __hip_atomic_fetch_add(&bcnt[it], 1u, __ATOMIC_RELEASE,
                                   __HIP_MEMORY_SCOPE_AGENT);
            while (__hip_atomic_load(&bcnt[it], __ATOMIC_ACQUIRE,
                                     __HIP_MEMORY_SCOPE_AGENT) < NBLK) {
                __builtin_amdgcn_s_sleep(1);
            }
            unsigned long long wv = __hip_atomic_load(&bslot[it], __ATOMIC_RELAXED,
                                                      __HIP_MEMORY_SCOPE_AGENT);
            unsigned int widx = ~(unsigned int)(wv & 0xFFFFFFFFull);
            scx = bxyz[3 * (size_t)widx + 0];
            scy = bxyz[3 * (size_t)widx + 1];
            scz = bxyz[3 * (size_t)widx + 2];
            if (chunk == 0) out[b * NSAMP + it] = (int)widx;
        }
        __syncthreads();
        cx = scx; cy = scy; cz = scz;
    }
}

extern "C" void kernel_launch(void* const* d_in, const int* in_sizes, int n_in,
                              void* d_out, int out_size, void* d_ws, size_t ws_size,
                              hipStream_t stream) {
    const float* xyz = (const float*)d_in[0];
    int* out = (int*)d_out;

    unsigned long long* slot = (unsigned long long*)d_ws;
    unsigned int* cnt = (unsigned int*)((char*)d_ws + (size_t)BATCH * NSAMP * 8);

    // Zero slots + counters (contiguous: BATCH*NSAMP*(8+4) bytes = 196608 u32)
    int initN = BATCH * NSAMP * 3;
    hipLaunchKernelGGL(fps_init_kernel, dim3((initN + 255) / 256), dim3(256), 0,
                       stream, (unsigned int*)d_ws, initN);

    hipLaunchKernelGGL(fps_kernel, dim3(BATCH * NBLK), dim3(TPB), 0, stream,
                       xyz, out, slot, cnt);
}

// Round 3
// 20206.171 us; speedup vs baseline: 1.1715x; 1.1715x over previous
//
#include <hip/hip_runtime.h>
#include <stdint.h>

// Problem: D-FPS. points_xyz (16, 131072, 3) fp32 -> indices (16, 4096) int32.
#define BATCH 16
#define NPTS  131072
#define NSAMP 4096
#define NBLK  16                  // blocks per batch
#define TPB   1024
#define CHUNK (NPTS / NBLK)       // 8192 points per block
#define PPT   (CHUNK / TPB)       // 8 points per thread, register-resident
#define NWAVE (TPB / 64)          // 16 waves per block

// Tagged slot layout (8B, atomically stored/loaded):
//   [63:32] dist float bits (non-negative -> monotone as uint)
//   [31:15] point index (17 bits, NPTS=2^17)
//   [14:0]  iteration tag (it < 4096). Poison 0xAA.. -> tag 0x2AAA=10922,
//           zero-init -> tag 0; neither matches a live it in [1,4095].
// Ring-2 by iteration parity: a writer can only be 2 iterations ahead after
// the reader's prior-parity reads completed (happens-before via the tagged
// release/acquire chain), so two buffers suffice.

static __device__ __forceinline__ unsigned long long
pack_tagged(unsigned int distBits, unsigned int idx, int it) {
    return ((unsigned long long)distBits << 32) |
           ((unsigned long long)idx << 15) | (unsigned long long)it;
}
// Comparison key: max dist, then min index (jnp.argmax first-occurrence).
static __device__ __forceinline__ unsigned long long
tagged_to_key(unsigned long long v) {
    unsigned int db  = (unsigned int)(v >> 32);
    unsigned int idx = (unsigned int)((v >> 15) & 0x1FFFFu);
    return ((unsigned long long)db << 32) | (unsigned long long)(~idx);
}

__global__ void fps_init_kernel(unsigned long long* __restrict__ gslot) {
    // Zero the 16*2*16 tagged slots (insurance against a launch without
    // workspace re-poison; tag 0 is never a live iteration).
    int i = blockIdx.x * blockDim.x + threadIdx.x;
    if (i < BATCH * 2 * NBLK) gslot[i] = 0ull;
}

__global__ __launch_bounds__(TPB, 4) void fps_kernel(
        const float* __restrict__ xyz, int* __restrict__ out,
        unsigned long long* __restrict__ gslot) {
    const int blk   = blockIdx.x;
    const int b     = blk & 15;        // batch = blk%16 -> a batch's 16 blocks
    const int chunk = blk >> 4;        // share blockIdx residue mod 8 (same XCD)
    const int tid   = threadIdx.x;
    const int w     = tid >> 6;
    const int lane  = tid & 63;

    const float* bxyz = xyz + (size_t)b * NPTS * 3;
    const int base = chunk * CHUNK;

    // Register-resident points + running min distance
    float px[PPT], py[PPT], pz[PPT], pd[PPT];
#pragma unroll
    for (int k = 0; k < PPT; ++k) {
        int p = base + tid + k * TPB;
        px[k] = bxyz[3 * (size_t)p + 0];
        py[k] = bxyz[3 * (size_t)p + 1];
        pz[k] = bxyz[3 * (size_t)p + 2];
        pd[k] = __builtin_inff();
    }

    __shared__ unsigned long long red[2][NWAVE];  // per-wave tagged bests
    __shared__ unsigned long long bc[2];          // tagged broadcast: it<<32|widx
    if (tid < 2 * NWAVE) ((unsigned long long*)red)[tid] = ~0ull; // tag 0x7FFF invalid
    if (tid < 2) bc[tid] = ~0ull;                                  // hi 0xFFFFFFFF invalid
    if (tid == 0 && chunk == 0) out[b * NSAMP] = 0;  // iteration 0 emits index 0
    __syncthreads();  // the only block-wide barrier (LDS init)

    float cx = bxyz[0], cy = bxyz[1], cz = bxyz[2];

    unsigned long long* gs = gslot + (size_t)b * 2 * NBLK;  // [2][NBLK]

    for (int it = 1; it < NSAMP; ++it) {
        const int par = it & 1;

        // ---- update min-dists + local argmax (registers only) ----
        // Verified arithmetic (round 2, absmax 0): FMA-contracted
        //   d = fma(dz,dz, fma(dy,dy, dx*dx)), subs exact-rounded.
        unsigned long long key = 0ull;
#pragma unroll
        for (int k = 0; k < PPT; ++k) {
            float dx = __fsub_rn(px[k], cx);
            float dy = __fsub_rn(py[k], cy);
            float dz = __fsub_rn(pz[k], cz);
            float d  = __builtin_fmaf(dz, dz,
                         __builtin_fmaf(dy, dy, __fmul_rn(dx, dx)));
            float nd = fminf(pd[k], d);
            pd[k] = nd;
            unsigned int gi = (unsigned int)(base + tid + k * TPB);
            unsigned long long pk =
                ((unsigned long long)__float_as_uint(nd) << 32) |
                (unsigned long long)(~gi);
            key = key > pk ? key : pk;
        }

        // ---- wave butterfly (64 lanes, 6 steps) ----
#pragma unroll
        for (int off = 1; off <= 32; off <<= 1) {
            unsigned long long o = __shfl_xor(key, off, 64);
            key = key > o ? key : o;
        }
        // lane0 publishes this wave's best to LDS (tagged, release)
        if (lane == 0) {
            unsigned int db  = (unsigned int)(key >> 32);
            unsigned int idx = ~(unsigned int)key;  // recover gi (fits 17 bits)
            __hip_atomic_store(&red[par][w], pack_tagged(db, idx, it),
                               __ATOMIC_RELEASE, __HIP_MEMORY_SCOPE_WORKGROUP);
        }

        if (w == 0) {
            // ---- combine the 16 wave entries (lanes 0..15 poll LDS) ----
            unsigned long long v; bool ok;
            do {
                v  = (lane < NWAVE)
                       ? __hip_atomic_load(&red[par][lane], __ATOMIC_ACQUIRE,
                                           __HIP_MEMORY_SCOPE_WORKGROUP)
                       : 0ull;
                ok = (lane < NWAVE) ? ((v & 0x7FFFull) == (unsigned long long)it)
                                    : true;
            } while (__ballot(ok) != ~0ull);
            unsigned long long k2 = (lane < NWAVE) ? tagged_to_key(v) : 0ull;
#pragma unroll
            for (int off = 1; off <= 8; off <<= 1) {
                unsigned long long o = __shfl_xor(k2, off, 64);
                k2 = k2 > o ? k2 : o;
            }
            // lane0 publishes block best globally (tagged, one release store)
            if (lane == 0) {
                unsigned int db  = (unsigned int)(k2 >> 32);
                unsigned int idx = ~(unsigned int)k2;
                __hip_atomic_store(&gs[par * NBLK + chunk],
                                   pack_tagged(db, idx, it),
                                   __ATOMIC_RELEASE, __HIP_MEMORY_SCOPE_AGENT);
            }
            // ---- poll all 16 block slots (one coalesced 128B load/round) ----
            do {
                v  = (lane < NBLK)
                       ? __hip_atomic_load(&gs[par * NBLK + lane], __ATOMIC_ACQUIRE,
                                           __HIP_MEMORY_SCOPE_AGENT)
                       : 0ull;
                ok = (lane < NBLK) ? ((v & 0x7FFFull) == (unsigned long long)it)
                                   : true;
            } while (__ballot(ok) != ~0ull);
            unsigned long long k3 = (lane < NBLK) ? tagged_to_key(v) : 0ull;
#pragma unroll
            for (int off = 1; off <= 8; off <<= 1) {
                unsigned long long o = __shfl_xor(k3, off, 64);
                k3 = k3 > o ? k3 : o;
            }
            if (lane == 0) {
                unsigned int widx = ~(unsigned int)k3;
                if (chunk == 0) out[b * NSAMP + it] = (int)widx;
                __hip_atomic_store(&bc[par],
                                   ((unsigned long long)(unsigned int)it << 32) |
                                       (unsigned long long)widx,
                                   __ATOMIC_RELEASE, __HIP_MEMORY_SCOPE_WORKGROUP);
            }
        }

        // ---- all waves: wait for tagged broadcast, fetch next centroid ----
        unsigned long long bv;
        do {
            bv = __hip_atomic_load(&bc[par], __ATOMIC_ACQUIRE,
                                   __HIP_MEMORY_SCOPE_WORKGROUP);
        } while ((unsigned int)(bv >> 32) != (unsigned int)it);
        unsigned int widx = (unsigned int)bv;
        cx = bxyz[3 * (size_t)widx + 0];
        cy = bxyz[3 * (size_t)widx + 1];
        cz = bxyz[3 * (size_t)widx + 2];
    }
}

extern "C" void kernel_launch(void* const* d_in, const int* in_sizes, int n_in,
                              void* d_out, int out_size, void* d_ws, size_t ws_size,
                              hipStream_t stream) {
    const float* xyz = (const float*)d_in[0];
    int* out = (int*)d_out;
    unsigned long long* gslot = (unsigned long long*)d_ws;  // [BATCH][2][NBLK]

    hipLaunchKernelGGL(fps_init_kernel, dim3(1), dim3(512), 0, stream, gslot);
    hipLaunchKernelGGL(fps_kernel, dim3(BATCH * NBLK), dim3(TPB), 0, stream,
                       xyz, out, gslot);
}